// Round 2
// 2478.078 us; speedup vs baseline: 1.9566x; 1.9566x over previous
//
#include <hip/hip_runtime.h>
#include <hip/hip_bf16.h>
#include <math.h>

typedef __hip_bfloat16 bf16;
typedef __bf16 bf16x8v __attribute__((ext_vector_type(8)));
typedef float f32x4 __attribute__((ext_vector_type(4)));
typedef unsigned short us8v __attribute__((ext_vector_type(8)));

// Problem dims
#define DD   1024
#define HH   16
#define DHD  64
#define EE   8
#define BB   4
#define LL   512
#define TT   2048
#define DFFD 4096
#define NLAT 2048   // B*L
#define NTOK 8192   // B*T
#define NASG 4096   // 2 * NLAT

__device__ __forceinline__ float toF(float x) { return x; }
__device__ __forceinline__ float toF(bf16 x) { return __bfloat162float(x); }
__device__ __forceinline__ float us2f(unsigned short u) {
    union { unsigned int i; float f; } v; v.i = ((unsigned int)u) << 16; return v.f;
}
__device__ __forceinline__ unsigned short f2us(float f) {
    bf16 t = __float2bfloat16(f);
    return *(unsigned short*)&t;
}

// ---------------- LayerNorm: one block (256 thr) per row, D=1024 --------------
__device__ __forceinline__ float block_sum256(float val, float* red) {
    #pragma unroll
    for (int off = 32; off > 0; off >>= 1) val += __shfl_down(val, off);
    if ((threadIdx.x & 63) == 0) red[threadIdx.x >> 6] = val;
    __syncthreads();
    if (threadIdx.x == 0) red[4] = red[0] + red[1] + red[2] + red[3];
    __syncthreads();
    float r = red[4];
    __syncthreads();
    return r;
}

__global__ __launch_bounds__(256) void ln_kernel(
    const float* __restrict__ x, const float* __restrict__ g, const float* __restrict__ b,
    bf16* __restrict__ out)
{
    __shared__ float red[5];
    int row = blockIdx.x;
    int tid = threadIdx.x;
    const float* xr = x + (size_t)row * DD;
    float v[4];
    #pragma unroll
    for (int i = 0; i < 4; ++i) v[i] = xr[tid + i * 256];
    float s = v[0] + v[1] + v[2] + v[3];
    float mean = block_sum256(s, red) * (1.0f / DD);
    float sq = 0.f;
    #pragma unroll
    for (int i = 0; i < 4; ++i) { float d = v[i] - mean; sq += d * d; }
    float var = block_sum256(sq, red) * (1.0f / DD);
    float rstd = rsqrtf(var + 1e-5f);
    bf16* orow = out + (size_t)row * DD;
    #pragma unroll
    for (int i = 0; i < 4; ++i) {
        int c = tid + i * 256;
        orow[c] = __float2bfloat16((v[i] - mean) * rstd * g[c] + b[c]);
    }
}

// ---------------- Generic GEMM: C[M,N] = A[M,K](bf16) * W[N,K](f32)^T + bias --
__global__ __launch_bounds__(256) void gemm_kernel(
    const bf16* __restrict__ A, const float* __restrict__ W,
    const float* __restrict__ bias,
    bf16* __restrict__ Cb, float* __restrict__ Cf,
    int M, int N, int K,
    const float* __restrict__ res,
    int act,
    const int* __restrict__ gather,
    const int* __restrict__ seg_off, const int* __restrict__ seg_cnt)
{
    int m_base = 0, mrows = M;
    if (seg_off) {
        int e = blockIdx.z;
        m_base = seg_off[e];
        mrows  = seg_cnt[e];
        W    += (size_t)e * N * K;
        bias += (size_t)e * N;
    }
    int m0 = blockIdx.y * 64;
    if (m0 >= mrows) return;
    int n0 = blockIdx.x * 64;

    __shared__ float As[16][68];
    __shared__ float Ws[16][68];

    int tid  = threadIdx.x;
    int la_r = tid >> 2;          // 0..63
    int la_k = (tid & 3) << 2;    // 0,4,8,12

    const bf16* aptr = nullptr;
    bool a_ok = (m0 + la_r) < mrows;
    if (a_ok) {
        int grow = m_base + m0 + la_r;
        int asrc = gather ? gather[grow] : grow;
        aptr = A + (size_t)asrc * K + la_k;
    }
    const float* wptr = W + (size_t)(n0 + la_r) * K + la_k;

    int cx = tid & 15, cy = tid >> 4;
    float acc[4][4] = {};

    for (int k0 = 0; k0 < K; k0 += 16) {
        ushort4 av = make_ushort4(0, 0, 0, 0);
        if (a_ok) av = *(const ushort4*)(aptr + k0);
        float4 wv = *(const float4*)(wptr + k0);
        As[la_k + 0][la_r] = us2f(av.x);
        As[la_k + 1][la_r] = us2f(av.y);
        As[la_k + 2][la_r] = us2f(av.z);
        As[la_k + 3][la_r] = us2f(av.w);
        Ws[la_k + 0][la_r] = wv.x;
        Ws[la_k + 1][la_r] = wv.y;
        Ws[la_k + 2][la_r] = wv.z;
        Ws[la_k + 3][la_r] = wv.w;
        __syncthreads();
        #pragma unroll
        for (int kk = 0; kk < 16; ++kk) {
            float4 a = *(const float4*)&As[kk][cy * 4];
            float4 b = *(const float4*)&Ws[kk][cx * 4];
            acc[0][0] += a.x * b.x; acc[0][1] += a.x * b.y; acc[0][2] += a.x * b.z; acc[0][3] += a.x * b.w;
            acc[1][0] += a.y * b.x; acc[1][1] += a.y * b.y; acc[1][2] += a.y * b.z; acc[1][3] += a.y * b.w;
            acc[2][0] += a.z * b.x; acc[2][1] += a.z * b.y; acc[2][2] += a.z * b.z; acc[2][3] += a.z * b.w;
            acc[3][0] += a.w * b.x; acc[3][1] += a.w * b.y; acc[3][2] += a.w * b.z; acc[3][3] += a.w * b.w;
        }
        __syncthreads();
    }

    int col0 = n0 + cx * 4;
    #pragma unroll
    for (int i = 0; i < 4; ++i) {
        int r = cy * 4 + i;
        if (m0 + r >= mrows) continue;
        size_t crow = (size_t)(m_base + m0 + r);
        float vals[4];
        #pragma unroll
        for (int j = 0; j < 4; ++j) {
            float v = acc[i][j] + bias[col0 + j];
            if (act == 1) v = 0.5f * v * (1.0f + erff(v * 0.70710678118654752f));
            if (res) v += res[crow * N + col0 + j];
            vals[j] = v;
        }
        if (Cb) {
            ushort4 o;
            o.x = f2us(vals[0]); o.y = f2us(vals[1]);
            o.z = f2us(vals[2]); o.w = f2us(vals[3]);
            *(ushort4*)(Cb + crow * N + col0) = o;
        } else {
            *(float4*)(Cf + crow * N + col0) = make_float4(vals[0], vals[1], vals[2], vals[3]);
        }
    }
}

// ---------------- Attention (MFMA flash): 4 waves/block, 64 q rows/block ------
// Swapped QK^T: S^T = mfma(A=K, B=Q); D layout col=lane&15 (=q), row=4*lg+reg
// (=key). Softmax per q-row is in-register + shfl_xor(16/32). P is carried in
// SPLIT bf16 (high + low residual) so P*V is effectively f32-accurate: the
// attention output then matches the scalar-f32 reference path to ~1e-6, which
// keeps the fp32 MoE routing decisions identical (top-2 flip safety).
__global__ __launch_bounds__(256) void attn_mfma_kernel(
    const bf16* __restrict__ Q, int ldq, int qoff,
    const bf16* __restrict__ KV, int ldk, int koff, int voff,
    bf16* __restrict__ O, int Lq, int Tk)
{
    __shared__ bf16 Qs[64][72];
    __shared__ bf16 Ks[32][72];
    __shared__ bf16 Vs[64][40];        // transposed V: [dh][k]
    __shared__ bf16 Psh[4][16][40];    // per-wave P tile [q][k], bf16 high
    __shared__ bf16 Psl[4][16][40];    // bf16 low residual (p - bf16(p))

    const int nqb = Lq >> 6;
    const int qb  = blockIdx.x % nqb;
    const int h   = (blockIdx.x / nqb) % HH;
    const int b   = blockIdx.x / (nqb * HH);

    const int tid  = threadIdx.x;
    const int wq   = tid >> 6;
    const int lane = tid & 63;
    const int lg   = lane >> 4;
    const int l16  = lane & 15;

    // ---- stage Q tile (pre-scaled by 1/sqrt(64)=0.125 — exact in bf16) ----
    {
        const int row = tid >> 2;
        const int c0  = (tid & 3) * 16;
        const unsigned short* src = (const unsigned short*)
            (Q + (size_t)(b * Lq + qb * 64 + row) * ldq + qoff + h * DHD + c0);
        #pragma unroll
        for (int hf = 0; hf < 2; ++hf) {
            us8v v = *(const us8v*)(src + hf * 8);
            us8v o;
            #pragma unroll
            for (int j = 0; j < 8; ++j) o[j] = f2us(us2f(v[j]) * 0.125f);
            *(us8v*)&Qs[row][c0 + hf * 8] = o;
        }
    }
    __syncthreads();

    const int qrow = wq * 16 + l16;
    const bf16x8v fQ0 = *(const bf16x8v*)&Qs[qrow][lg * 8];
    const bf16x8v fQ1 = *(const bf16x8v*)&Qs[qrow][32 + lg * 8];

    float m = -1e30f, lsum = 0.f;
    f32x4 Of[4] = {};

    const size_t kvbase = (size_t)b * Tk * ldk;
    const int kst_k = tid >> 3;          // 0..31
    const int kst_c = (tid & 7) * 8;     // dh chunk
    const int vst_k = (tid & 15) * 2;    // key pair
    const int vst_d = (tid >> 4) * 4;    // dh base

    for (int t0 = 0; t0 < Tk; t0 += 32) {
        // stage K tile [32][64]
        {
            const bf16* ks = KV + kvbase + (size_t)(t0 + kst_k) * ldk + koff + h * DHD + kst_c;
            *(float4*)&Ks[kst_k][kst_c] = *(const float4*)ks;
        }
        // stage V tile transposed -> Vs[dh][k]
        {
            const bf16* vsrc = KV + kvbase + (size_t)(t0 + vst_k) * ldk + voff + h * DHD + vst_d;
            ushort4 a = *(const ushort4*)vsrc;
            ushort4 c = *(const ushort4*)(vsrc + ldk);
            unsigned int w;
            w = (unsigned)a.x | ((unsigned)c.x << 16); *(unsigned*)&Vs[vst_d + 0][vst_k] = w;
            w = (unsigned)a.y | ((unsigned)c.y << 16); *(unsigned*)&Vs[vst_d + 1][vst_k] = w;
            w = (unsigned)a.z | ((unsigned)c.z << 16); *(unsigned*)&Vs[vst_d + 2][vst_k] = w;
            w = (unsigned)a.w | ((unsigned)c.w << 16); *(unsigned*)&Vs[vst_d + 3][vst_k] = w;
        }
        __syncthreads();

        // ---- QK^T: S^T[k][q], keys 0..15 in st0, 16..31 in st1 ----
        f32x4 st0 = {}, st1 = {};
        {
            const bf16x8v k00 = *(const bf16x8v*)&Ks[l16][lg * 8];
            const bf16x8v k10 = *(const bf16x8v*)&Ks[16 + l16][lg * 8];
            const bf16x8v k01 = *(const bf16x8v*)&Ks[l16][32 + lg * 8];
            const bf16x8v k11 = *(const bf16x8v*)&Ks[16 + l16][32 + lg * 8];
            st0 = __builtin_amdgcn_mfma_f32_16x16x32_bf16(k00, fQ0, st0, 0, 0, 0);
            st1 = __builtin_amdgcn_mfma_f32_16x16x32_bf16(k10, fQ0, st1, 0, 0, 0);
            st0 = __builtin_amdgcn_mfma_f32_16x16x32_bf16(k01, fQ1, st0, 0, 0, 0);
            st1 = __builtin_amdgcn_mfma_f32_16x16x32_bf16(k11, fQ1, st1, 0, 0, 0);
        }

        // ---- online softmax for row q = l16 (f32, expf: matches reference) ----
        float cm = fmaxf(fmaxf(fmaxf(st0[0], st0[1]), fmaxf(st0[2], st0[3])),
                         fmaxf(fmaxf(st1[0], st1[1]), fmaxf(st1[2], st1[3])));
        cm = fmaxf(cm, __shfl_xor(cm, 16));
        cm = fmaxf(cm, __shfl_xor(cm, 32));
        const float nm = fmaxf(m, cm);
        float p0[4], p1[4];
        float ps = 0.f;
        #pragma unroll
        for (int r = 0; r < 4; ++r) { p0[r] = expf(st0[r] - nm); ps += p0[r]; }
        #pragma unroll
        for (int r = 0; r < 4; ++r) { p1[r] = expf(st1[r] - nm); ps += p1[r]; }
        ps += __shfl_xor(ps, 16);
        ps += __shfl_xor(ps, 32);
        const float alpha = expf(m - nm);
        lsum = lsum * alpha + ps;
        m = nm;

        // ---- write split-P tile: Psh = bf16(p), Psl = bf16(p - Psh) ----
        ushort4 h0, h1, lo0, lo1;
        #pragma unroll
        for (int r = 0; r < 4; ++r) {
            unsigned short hh = f2us(p0[r]);
            ((unsigned short*)&h0)[r]  = hh;
            ((unsigned short*)&lo0)[r] = f2us(p0[r] - us2f(hh));
        }
        #pragma unroll
        for (int r = 0; r < 4; ++r) {
            unsigned short hh = f2us(p1[r]);
            ((unsigned short*)&h1)[r]  = hh;
            ((unsigned short*)&lo1)[r] = f2us(p1[r] - us2f(hh));
        }
        *(ushort4*)&Psh[wq][l16][lg * 4]      = h0;
        *(ushort4*)&Psh[wq][l16][16 + lg * 4] = h1;
        *(ushort4*)&Psl[wq][l16][lg * 4]      = lo0;
        *(ushort4*)&Psl[wq][l16][16 + lg * 4] = lo1;

        // ---- rescale O accumulators (row q' = 4*lg + r) ----
        #pragma unroll
        for (int r = 0; r < 4; ++r) {
            const float ar = __shfl(alpha, lg * 4 + r);
            Of[0][r] *= ar; Of[1][r] *= ar; Of[2][r] *= ar; Of[3][r] *= ar;
        }

        __syncthreads();   // P writes visible before re-read (belt & suspenders)

        // ---- PV: O[q][dh] += (Ph + Pl)[q][k] * V[k][dh] ----
        const bf16x8v pah = *(const bf16x8v*)&Psh[wq][l16][lg * 8];
        const bf16x8v pal = *(const bf16x8v*)&Psl[wq][l16][lg * 8];
        #pragma unroll
        for (int bb = 0; bb < 4; ++bb) {
            const bf16x8v bv = *(const bf16x8v*)&Vs[bb * 16 + l16][lg * 8];
            Of[bb] = __builtin_amdgcn_mfma_f32_16x16x32_bf16(pal, bv, Of[bb], 0, 0, 0);
            Of[bb] = __builtin_amdgcn_mfma_f32_16x16x32_bf16(pah, bv, Of[bb], 0, 0, 0);
        }
        __syncthreads();   // protect Ks/Vs before next-tile staging
    }

    // ---- epilogue: divide by row sums, store bf16 ----
    #pragma unroll
    for (int r = 0; r < 4; ++r) {
        const float inv = 1.0f / __shfl(lsum, lg * 4 + r);
        const int grow = b * Lq + qb * 64 + wq * 16 + lg * 4 + r;
        bf16* orow = O + (size_t)grow * DD + h * DHD;
        #pragma unroll
        for (int bb = 0; bb < 4; ++bb)
            orow[bb * 16 + l16] = __float2bfloat16(Of[bb][r] * inv);
    }
}

// ---------------- MoE router: fp32 LN recomputed in-kernel ----------
__global__ __launch_bounds__(64) void router_kernel(
    const float* __restrict__ X2,
    const float* __restrict__ g, const float* __restrict__ b,
    const float* __restrict__ rw, const float* __restrict__ rb,
    float* __restrict__ gates, int* __restrict__ ebuf, int* __restrict__ counts)
{
    int n = blockIdx.x;
    int lane = threadIdx.x;
    const float* xr = X2 + (size_t)n * DD;

    float v[16];
    #pragma unroll
    for (int i = 0; i < 16; ++i) v[i] = xr[lane + i * 64];

    float s = 0.f;
    #pragma unroll
    for (int i = 0; i < 16; ++i) s += v[i];
    #pragma unroll
    for (int off = 32; off > 0; off >>= 1) s += __shfl_xor(s, off);
    float mean = s * (1.0f / DD);

    float sq = 0.f;
    #pragma unroll
    for (int i = 0; i < 16; ++i) { float d = v[i] - mean; sq += d * d; }
    #pragma unroll
    for (int off = 32; off > 0; off >>= 1) sq += __shfl_xor(sq, off);
    float rstd = rsqrtf(sq * (1.0f / DD) + 1e-5f);

    float h[16];
    #pragma unroll
    for (int i = 0; i < 16; ++i) {
        int c = lane + i * 64;
        h[i] = (v[i] - mean) * rstd * g[c] + b[c];
    }

    float logit[EE];
    #pragma unroll
    for (int e = 0; e < EE; ++e) {
        const float* wr = rw + (size_t)e * DD;
        float p = 0.f;
        #pragma unroll
        for (int i = 0; i < 16; ++i) p += h[i] * wr[lane + i * 64];
        #pragma unroll
        for (int off = 32; off > 0; off >>= 1) p += __shfl_xor(p, off);
        logit[e] = p;
    }

    if (lane == 0) {
        #pragma unroll
        for (int e = 0; e < EE; ++e) logit[e] += rb[e];
        int i0 = 0;
        #pragma unroll
        for (int e = 1; e < EE; ++e) if (logit[e] > logit[i0]) i0 = e;
        int i1 = -1;
        #pragma unroll
        for (int e = 0; e < EE; ++e) {
            if (e == i0) continue;
            if (i1 < 0 || logit[e] > logit[i1]) i1 = e;
        }
        float ex = expf(logit[i1] - logit[i0]);
        float inv = 1.0f / (1.0f + ex);
        gates[2 * n + 0] = inv;
        gates[2 * n + 1] = ex * inv;
        ebuf[2 * n + 0] = i0;
        ebuf[2 * n + 1] = i1;
        atomicAdd(&counts[i0], 1);
        atomicAdd(&counts[i1], 1);
    }
}

__global__ void zero8_kernel(int* __restrict__ p) {
    if (threadIdx.x < EE) p[threadIdx.x] = 0;
}

__global__ void prefix_kernel(const int* __restrict__ counts,
                              int* __restrict__ seg_off, int* __restrict__ cursors) {
    if (threadIdx.x == 0) {
        int acc = 0;
        for (int e = 0; e < EE; ++e) { seg_off[e] = acc; cursors[e] = acc; acc += counts[e]; }
    }
}

__global__ __launch_bounds__(256) void scatter_kernel(
    const int* __restrict__ ebuf, int* __restrict__ cursors,
    int* __restrict__ tok_list, int* __restrict__ r_of)
{
    int n = blockIdx.x * 256 + threadIdx.x;
    if (n < NLAT) {
        for (int k = 0; k < 2; ++k) {
            int e = ebuf[2 * n + k];
            int r = atomicAdd(&cursors[e], 1);
            tok_list[r] = n;
            r_of[2 * n + k] = r;
        }
    }
}

__global__ __launch_bounds__(256) void mix_kernel(
    const float* __restrict__ X2, const bf16* __restrict__ EOUT,
    const float* __restrict__ gates, const int* __restrict__ r_of,
    float* __restrict__ out)
{
    int id = blockIdx.x * 256 + threadIdx.x;   // < NLAT*DD
    int n = id >> 10;
    int d = id & 1023;
    float v = X2[id]
            + gates[2 * n + 0] * toF(EOUT[(size_t)r_of[2 * n + 0] * DD + d])
            + gates[2 * n + 1] * toF(EOUT[(size_t)r_of[2 * n + 1] * DD + d]);
    out[id] = v;
}

// ---------------- Launcher ----------------
extern "C" void kernel_launch(void* const* d_in, const int* in_sizes, int n_in,
                              void* d_out, int out_size, void* d_ws, size_t ws_size,
                              hipStream_t stream)
{
    const float* latents  = (const float*)d_in[0];
    const float* tokens   = (const float*)d_in[1];
    const float* sa_ln_g  = (const float*)d_in[2];
    const float* sa_ln_b  = (const float*)d_in[3];
    const float* sa_in_w  = (const float*)d_in[4];
    const float* sa_in_b  = (const float*)d_in[5];
    const float* sa_out_w = (const float*)d_in[6];
    const float* sa_out_b = (const float*)d_in[7];
    const float* ca_q_ln_g  = (const float*)d_in[8];
    const float* ca_q_ln_b  = (const float*)d_in[9];
    const float* ca_kv_ln_g = (const float*)d_in[10];
    const float* ca_kv_ln_b = (const float*)d_in[11];
    const float* ca_in_w  = (const float*)d_in[12];
    const float* ca_in_b  = (const float*)d_in[13];
    const float* ca_out_w = (const float*)d_in[14];
    const float* ca_out_b = (const float*)d_in[15];
    const float* moe_ln_g = (const float*)d_in[16];
    const float* moe_ln_b = (const float*)d_in[17];
    const float* router_w = (const float*)d_in[18];
    const float* router_b = (const float*)d_in[19];
    const float* e_fc1_w  = (const float*)d_in[20];
    const float* e_fc1_b  = (const float*)d_in[21];
    const float* e_fc2_w  = (const float*)d_in[22];
    const float* e_fc2_b  = (const float*)d_in[23];

    // ---- workspace layout (liveness-based reuse; peak ~76 MB) ----
    char* base = (char*)d_ws;
    const size_t MB = (size_t)1 << 20;
    float* X1   = (float*)(base + 0 * MB);
    float* X2   = (float*)(base + 8 * MB);
    bf16*  H    = (bf16*) (base + 16 * MB);
    bf16*  AO   = (bf16*) (base + 20 * MB);
    bf16*  QCA  = (bf16*) (base + 24 * MB);
    bf16*  KVLN = (bf16*) (base + 28 * MB);
    bf16*  EOUT = (bf16*) (base + 28 * MB);
    bf16*  KVCA = (bf16*) (base + 44 * MB);
    bf16*  QKV  = (bf16*) (base + 44 * MB);
    bf16*  H1   = (bf16*) (base + 44 * MB);
    float* GATES = (float*)(base + 76 * MB);
    int* ebuf     = (int*)(base + 76 * MB + 16384);
    int* tok_list = ebuf + NASG;
    int* r_of     = tok_list + NASG;
    int* counts   = r_of + NASG;
    int* seg_off  = counts + EE;
    int* cursors  = seg_off + EE;

    // 1. SA LN
    ln_kernel<<<NLAT, 256, 0, stream>>>(latents, sa_ln_g, sa_ln_b, H);
    // 2. SA QKV projection
    {
        dim3 g(3072 / 64, NLAT / 64, 1);
        gemm_kernel<<<g, 256, 0, stream>>>(H, sa_in_w, sa_in_b, QKV, nullptr,
                                           NLAT, 3072, DD,
                                           nullptr, 0, nullptr, nullptr, nullptr);
    }
    // 3. SA attention (MFMA flash)
    attn_mfma_kernel<<<BB * HH * (LL / 64), 256, 0, stream>>>(
        QKV, 3072, 0, QKV, 3072, 1024, 2048, AO, LL, LL);
    // 4. X1 = latents + AO @ sa_out_w^T + b
    {
        dim3 g(DD / 64, NLAT / 64, 1);
        gemm_kernel<<<g, 256, 0, stream>>>(AO, sa_out_w, sa_out_b, nullptr, X1,
                                           NLAT, DD, DD,
                                           latents, 0, nullptr, nullptr, nullptr);
    }
    // 5. CA q-LN
    ln_kernel<<<NLAT, 256, 0, stream>>>(X1, ca_q_ln_g, ca_q_ln_b, H);
    // 6. CA kv-LN of tokens
    ln_kernel<<<NTOK, 256, 0, stream>>>(tokens, ca_kv_ln_g, ca_kv_ln_b, KVLN);
    // 7. CA Q projection
    {
        dim3 g(DD / 64, NLAT / 64, 1);
        gemm_kernel<<<g, 256, 0, stream>>>(H, ca_in_w, ca_in_b, QCA, nullptr,
                                           NLAT, DD, DD,
                                           nullptr, 0, nullptr, nullptr, nullptr);
    }
    // 8. CA K,V projection
    {
        dim3 g(2048 / 64, NTOK / 64, 1);
        gemm_kernel<<<g, 256, 0, stream>>>(KVLN, ca_in_w + (size_t)1024 * DD, ca_in_b + 1024,
                                           KVCA, nullptr, NTOK, 2048, DD,
                                           nullptr, 0, nullptr, nullptr, nullptr);
    }
    // 9. CA attention (MFMA flash)
    attn_mfma_kernel<<<BB * HH * (LL / 64), 256, 0, stream>>>(
        QCA, 1024, 0, KVCA, 2048, 0, 1024, AO, LL, TT);
    // 10. X2 = X1 + AO @ ca_out_w^T + b
    {
        dim3 g(DD / 64, NLAT / 64, 1);
        gemm_kernel<<<g, 256, 0, stream>>>(AO, ca_out_w, ca_out_b, nullptr, X2,
                                           NLAT, DD, DD,
                                           X1, 0, nullptr, nullptr, nullptr);
    }
    // 11. MoE LN
    ln_kernel<<<NLAT, 256, 0, stream>>>(X2, moe_ln_g, moe_ln_b, H);
    // 12-15. Routing
    zero8_kernel<<<1, 64, 0, stream>>>(counts);
    router_kernel<<<NLAT, 64, 0, stream>>>(X2, moe_ln_g, moe_ln_b, router_w, router_b,
                                           GATES, ebuf, counts);
    prefix_kernel<<<1, 64, 0, stream>>>(counts, seg_off, cursors);
    scatter_kernel<<<NLAT / 256, 256, 0, stream>>>(ebuf, cursors, tok_list, r_of);
    // 16. fc1 grouped (gelu)
    {
        dim3 g(DFFD / 64, NLAT / 64, EE);
        gemm_kernel<<<g, 256, 0, stream>>>(H, e_fc1_w, e_fc1_b, H1, nullptr,
                                           0, DFFD, DD,
                                           nullptr, 1, tok_list, seg_off, counts);
    }
    // 17. fc2 grouped
    {
        dim3 g(DD / 64, NLAT / 64, EE);
        gemm_kernel<<<g, 256, 0, stream>>>(H1, e_fc2_w, e_fc2_b, EOUT, nullptr,
                                           0, DD, DFFD,
                                           nullptr, 0, nullptr, seg_off, counts);
    }
    // 18. Mix + residual
    mix_kernel<<<(NLAT * DD) / 256, 256, 0, stream>>>(X2, EOUT, GATES, r_of, (float*)d_out);
}

// Round 3
// 1211.760 us; speedup vs baseline: 4.0014x; 2.0450x over previous
//
#include <hip/hip_runtime.h>
#include <hip/hip_bf16.h>
#include <math.h>

typedef __hip_bfloat16 bf16;
typedef __bf16 bf16x8v __attribute__((ext_vector_type(8)));
typedef float f32x4 __attribute__((ext_vector_type(4)));
typedef unsigned short us8v __attribute__((ext_vector_type(8)));

// Problem dims
#define DD   1024
#define HH   16
#define DHD  64
#define EE   8
#define BB   4
#define LL   512
#define TT   2048
#define DFFD 4096
#define NLAT 2048   // B*L
#define NTOK 8192   // B*T
#define NASG 4096   // 2 * NLAT

__device__ __forceinline__ float toF(float x) { return x; }
__device__ __forceinline__ float toF(bf16 x) { return __bfloat162float(x); }
__device__ __forceinline__ float us2f(unsigned short u) {
    union { unsigned int i; float f; } v; v.i = ((unsigned int)u) << 16; return v.f;
}
__device__ __forceinline__ unsigned short f2us(float f) {
    bf16 t = __float2bfloat16(f);
    return *(unsigned short*)&t;
}

// ---------------- LayerNorm: one block (256 thr) per row, D=1024 --------------
__device__ __forceinline__ float block_sum256(float val, float* red) {
    #pragma unroll
    for (int off = 32; off > 0; off >>= 1) val += __shfl_down(val, off);
    if ((threadIdx.x & 63) == 0) red[threadIdx.x >> 6] = val;
    __syncthreads();
    if (threadIdx.x == 0) red[4] = red[0] + red[1] + red[2] + red[3];
    __syncthreads();
    float r = red[4];
    __syncthreads();
    return r;
}

__global__ __launch_bounds__(256) void ln_kernel(
    const float* __restrict__ x, const float* __restrict__ g, const float* __restrict__ b,
    bf16* __restrict__ out)
{
    __shared__ float red[5];
    int row = blockIdx.x;
    int tid = threadIdx.x;
    const float* xr = x + (size_t)row * DD;
    float v[4];
    #pragma unroll
    for (int i = 0; i < 4; ++i) v[i] = xr[tid + i * 256];
    float s = v[0] + v[1] + v[2] + v[3];
    float mean = block_sum256(s, red) * (1.0f / DD);
    float sq = 0.f;
    #pragma unroll
    for (int i = 0; i < 4; ++i) { float d = v[i] - mean; sq += d * d; }
    float var = block_sum256(sq, red) * (1.0f / DD);
    float rstd = rsqrtf(var + 1e-5f);
    bf16* orow = out + (size_t)row * DD;
    #pragma unroll
    for (int i = 0; i < 4; ++i) {
        int c = tid + i * 256;
        orow[c] = __float2bfloat16((v[i] - mean) * rstd * g[c] + b[c]);
    }
}

// ---------------- MFMA GEMM: C[M,N] = A[M,K](bf16) * W[N,K](f32->bf16)^T ------
// 128x128 tile, BK=32, 256 threads / 4 waves (each wave = 64x64 out).
// W is converted on-the-fly: split==1 stages Wh=bf16(W) AND Wl=bf16(W-Wh) and
// does 2 MFMAs (18-bit-accurate weights -> routing-safe); split==0 stages Wh only.
// Layout per verified attn kernel: mfma(A_frag,B_frag): A lane&15 = out-row
// (distributed over lg,reg in D), B lane&15 = out-col. k-major LDS [kg][row][8].
__global__ __launch_bounds__(256) void mfma_gemm_kernel(
    const bf16* __restrict__ A, const float* __restrict__ W,
    const float* __restrict__ bias,
    bf16* __restrict__ Cb, float* __restrict__ Cf,
    int M, int N, int K,
    const float* __restrict__ res, int act, int split,
    const int* __restrict__ gather,
    const int* __restrict__ seg_off, const int* __restrict__ seg_cnt)
{
    int m_base = 0, mrows = M;
    if (seg_off) {
        int e = blockIdx.z;
        m_base = seg_off[e];
        mrows  = seg_cnt[e];
        W    += (size_t)e * N * K;
        bias += (size_t)e * N;
    }
    const int m0 = blockIdx.y * 128;
    if (m0 >= mrows) return;
    const int n0 = blockIdx.x * 128;

    __shared__ bf16 As[4][128][8];   // [k-group][m][8]  (16B frags)
    __shared__ bf16 Wh[4][128][8];   // [k-group][n][8]
    __shared__ bf16 Wl[4][128][8];

    const int tid  = threadIdx.x;
    const int wid  = tid >> 6;
    const int lane = tid & 63;
    const int lg   = lane >> 4;
    const int l16  = lane & 15;
    const int mb   = (wid >> 1) * 64;   // wave row base in tile
    const int nb   = (wid & 1) * 64;    // wave col base in tile

    const int srow  = tid >> 1;         // 0..127 staging row
    const int shalf = tid & 1;          // which 16-k half
    const int kg0   = shalf * 2;

    const bool a_ok = (m0 + srow) < mrows;
    const unsigned short* aptr = nullptr;
    if (a_ok) {
        int grow = m_base + m0 + srow;
        int asrc = gather ? gather[grow] : grow;
        aptr = (const unsigned short*)(A + (size_t)asrc * K + shalf * 16);
    }
    const float* wptr = W + (size_t)(n0 + srow) * K + shalf * 16;

    f32x4 acc[4][4] = {};

    for (int k0 = 0; k0 < K; k0 += 32) {
        us8v av0 = {0,0,0,0,0,0,0,0}, av1 = {0,0,0,0,0,0,0,0};
        if (a_ok) {
            av0 = *(const us8v*)(aptr + k0);
            av1 = *(const us8v*)(aptr + k0 + 8);
        }
        float4 w0 = *(const float4*)(wptr + k0);
        float4 w1 = *(const float4*)(wptr + k0 + 4);
        float4 w2 = *(const float4*)(wptr + k0 + 8);
        float4 w3 = *(const float4*)(wptr + k0 + 12);

        us8v hi0, hi1, lo0, lo1;
        {
            const float fw[16] = {w0.x, w0.y, w0.z, w0.w, w1.x, w1.y, w1.z, w1.w,
                                  w2.x, w2.y, w2.z, w2.w, w3.x, w3.y, w3.z, w3.w};
            #pragma unroll
            for (int j = 0; j < 8; ++j) {
                unsigned short h0 = f2us(fw[j]);
                unsigned short h1 = f2us(fw[j + 8]);
                hi0[j] = h0; hi1[j] = h1;
                lo0[j] = f2us(fw[j] - us2f(h0));
                lo1[j] = f2us(fw[j + 8] - us2f(h1));
            }
        }
        *(us8v*)&As[kg0][srow][0]     = av0;
        *(us8v*)&As[kg0 + 1][srow][0] = av1;
        *(us8v*)&Wh[kg0][srow][0]     = hi0;
        *(us8v*)&Wh[kg0 + 1][srow][0] = hi1;
        if (split) {
            *(us8v*)&Wl[kg0][srow][0]     = lo0;
            *(us8v*)&Wl[kg0 + 1][srow][0] = lo1;
        }
        __syncthreads();

        bf16x8v af[4], wf[4];
        #pragma unroll
        for (int i = 0; i < 4; ++i) af[i] = *(const bf16x8v*)&As[lg][mb + i * 16 + l16][0];
        if (split) {
            bf16x8v wlf[4];
            #pragma unroll
            for (int j = 0; j < 4; ++j) wlf[j] = *(const bf16x8v*)&Wl[lg][nb + j * 16 + l16][0];
            #pragma unroll
            for (int i = 0; i < 4; ++i)
                #pragma unroll
                for (int j = 0; j < 4; ++j)
                    acc[i][j] = __builtin_amdgcn_mfma_f32_16x16x32_bf16(af[i], wlf[j], acc[i][j], 0, 0, 0);
        }
        #pragma unroll
        for (int j = 0; j < 4; ++j) wf[j] = *(const bf16x8v*)&Wh[lg][nb + j * 16 + l16][0];
        #pragma unroll
        for (int i = 0; i < 4; ++i)
            #pragma unroll
            for (int j = 0; j < 4; ++j)
                acc[i][j] = __builtin_amdgcn_mfma_f32_16x16x32_bf16(af[i], wf[j], acc[i][j], 0, 0, 0);
        __syncthreads();
    }

    // ---- epilogue: D layout col=l16 (n), row = lg*4 + reg (m within 16) ----
    #pragma unroll
    for (int i = 0; i < 4; ++i) {
        #pragma unroll
        for (int r = 0; r < 4; ++r) {
            int mm = m0 + mb + i * 16 + lg * 4 + r;
            if (mm >= mrows) continue;
            size_t crow = (size_t)(m_base + mm);
            #pragma unroll
            for (int j = 0; j < 4; ++j) {
                int nn = n0 + nb + j * 16 + l16;
                float v = acc[i][j][r] + bias[nn];
                if (act == 1) v = 0.5f * v * (1.0f + erff(v * 0.70710678118654752f));
                if (res) v += res[crow * (size_t)N + nn];
                if (Cb) Cb[crow * (size_t)N + nn] = __float2bfloat16(v);
                else    Cf[crow * (size_t)N + nn] = v;
            }
        }
    }
}

// ---------------- Attention (MFMA flash): 4 waves/block, 64 q rows/block ------
// Swapped QK^T: S^T = mfma(A=K, B=Q); D layout col=lane&15 (=q), row=4*lg+reg
// (=key). Softmax per q-row is in-register + shfl_xor(16/32). P is carried in
// SPLIT bf16 (high + low residual) so P*V is effectively f32-accurate: the
// attention output then matches the scalar-f32 reference path to ~1e-6, which
// keeps the fp32 MoE routing decisions identical (top-2 flip safety).
__global__ __launch_bounds__(256) void attn_mfma_kernel(
    const bf16* __restrict__ Q, int ldq, int qoff,
    const bf16* __restrict__ KV, int ldk, int koff, int voff,
    bf16* __restrict__ O, int Lq, int Tk)
{
    __shared__ bf16 Qs[64][72];
    __shared__ bf16 Ks[32][72];
    __shared__ bf16 Vs[64][40];        // transposed V: [dh][k]
    __shared__ bf16 Psh[4][16][40];    // per-wave P tile [q][k], bf16 high
    __shared__ bf16 Psl[4][16][40];    // bf16 low residual (p - bf16(p))

    const int nqb = Lq >> 6;
    const int qb  = blockIdx.x % nqb;
    const int h   = (blockIdx.x / nqb) % HH;
    const int b   = blockIdx.x / (nqb * HH);

    const int tid  = threadIdx.x;
    const int wq   = tid >> 6;
    const int lane = tid & 63;
    const int lg   = lane >> 4;
    const int l16  = lane & 15;

    // ---- stage Q tile (pre-scaled by 1/sqrt(64)=0.125 — exact in bf16) ----
    {
        const int row = tid >> 2;
        const int c0  = (tid & 3) * 16;
        const unsigned short* src = (const unsigned short*)
            (Q + (size_t)(b * Lq + qb * 64 + row) * ldq + qoff + h * DHD + c0);
        #pragma unroll
        for (int hf = 0; hf < 2; ++hf) {
            us8v v = *(const us8v*)(src + hf * 8);
            us8v o;
            #pragma unroll
            for (int j = 0; j < 8; ++j) o[j] = f2us(us2f(v[j]) * 0.125f);
            *(us8v*)&Qs[row][c0 + hf * 8] = o;
        }
    }
    __syncthreads();

    const int qrow = wq * 16 + l16;
    const bf16x8v fQ0 = *(const bf16x8v*)&Qs[qrow][lg * 8];
    const bf16x8v fQ1 = *(const bf16x8v*)&Qs[qrow][32 + lg * 8];

    float m = -1e30f, lsum = 0.f;
    f32x4 Of[4] = {};

    const size_t kvbase = (size_t)b * Tk * ldk;
    const int kst_k = tid >> 3;          // 0..31
    const int kst_c = (tid & 7) * 8;     // dh chunk
    const int vst_k = (tid & 15) * 2;    // key pair
    const int vst_d = (tid >> 4) * 4;    // dh base

    for (int t0 = 0; t0 < Tk; t0 += 32) {
        // stage K tile [32][64]
        {
            const bf16* ks = KV + kvbase + (size_t)(t0 + kst_k) * ldk + koff + h * DHD + kst_c;
            *(float4*)&Ks[kst_k][kst_c] = *(const float4*)ks;
        }
        // stage V tile transposed -> Vs[dh][k]
        {
            const bf16* vsrc = KV + kvbase + (size_t)(t0 + vst_k) * ldk + voff + h * DHD + vst_d;
            ushort4 a = *(const ushort4*)vsrc;
            ushort4 c = *(const ushort4*)(vsrc + ldk);
            unsigned int w;
            w = (unsigned)a.x | ((unsigned)c.x << 16); *(unsigned*)&Vs[vst_d + 0][vst_k] = w;
            w = (unsigned)a.y | ((unsigned)c.y << 16); *(unsigned*)&Vs[vst_d + 1][vst_k] = w;
            w = (unsigned)a.z | ((unsigned)c.z << 16); *(unsigned*)&Vs[vst_d + 2][vst_k] = w;
            w = (unsigned)a.w | ((unsigned)c.w << 16); *(unsigned*)&Vs[vst_d + 3][vst_k] = w;
        }
        __syncthreads();

        // ---- QK^T: S^T[k][q], keys 0..15 in st0, 16..31 in st1 ----
        f32x4 st0 = {}, st1 = {};
        {
            const bf16x8v k00 = *(const bf16x8v*)&Ks[l16][lg * 8];
            const bf16x8v k10 = *(const bf16x8v*)&Ks[16 + l16][lg * 8];
            const bf16x8v k01 = *(const bf16x8v*)&Ks[l16][32 + lg * 8];
            const bf16x8v k11 = *(const bf16x8v*)&Ks[16 + l16][32 + lg * 8];
            st0 = __builtin_amdgcn_mfma_f32_16x16x32_bf16(k00, fQ0, st0, 0, 0, 0);
            st1 = __builtin_amdgcn_mfma_f32_16x16x32_bf16(k10, fQ0, st1, 0, 0, 0);
            st0 = __builtin_amdgcn_mfma_f32_16x16x32_bf16(k01, fQ1, st0, 0, 0, 0);
            st1 = __builtin_amdgcn_mfma_f32_16x16x32_bf16(k11, fQ1, st1, 0, 0, 0);
        }

        // ---- online softmax for row q = l16 (f32, expf: matches reference) ----
        float cm = fmaxf(fmaxf(fmaxf(st0[0], st0[1]), fmaxf(st0[2], st0[3])),
                         fmaxf(fmaxf(st1[0], st1[1]), fmaxf(st1[2], st1[3])));
        cm = fmaxf(cm, __shfl_xor(cm, 16));
        cm = fmaxf(cm, __shfl_xor(cm, 32));
        const float nm = fmaxf(m, cm);
        float p0[4], p1[4];
        float ps = 0.f;
        #pragma unroll
        for (int r = 0; r < 4; ++r) { p0[r] = expf(st0[r] - nm); ps += p0[r]; }
        #pragma unroll
        for (int r = 0; r < 4; ++r) { p1[r] = expf(st1[r] - nm); ps += p1[r]; }
        ps += __shfl_xor(ps, 16);
        ps += __shfl_xor(ps, 32);
        const float alpha = expf(m - nm);
        lsum = lsum * alpha + ps;
        m = nm;

        // ---- write split-P tile: Psh = bf16(p), Psl = bf16(p - Psh) ----
        ushort4 h0, h1, lo0, lo1;
        #pragma unroll
        for (int r = 0; r < 4; ++r) {
            unsigned short hh = f2us(p0[r]);
            ((unsigned short*)&h0)[r]  = hh;
            ((unsigned short*)&lo0)[r] = f2us(p0[r] - us2f(hh));
        }
        #pragma unroll
        for (int r = 0; r < 4; ++r) {
            unsigned short hh = f2us(p1[r]);
            ((unsigned short*)&h1)[r]  = hh;
            ((unsigned short*)&lo1)[r] = f2us(p1[r] - us2f(hh));
        }
        *(ushort4*)&Psh[wq][l16][lg * 4]      = h0;
        *(ushort4*)&Psh[wq][l16][16 + lg * 4] = h1;
        *(ushort4*)&Psl[wq][l16][lg * 4]      = lo0;
        *(ushort4*)&Psl[wq][l16][16 + lg * 4] = lo1;

        // ---- rescale O accumulators (row q' = 4*lg + r) ----
        #pragma unroll
        for (int r = 0; r < 4; ++r) {
            const float ar = __shfl(alpha, lg * 4 + r);
            Of[0][r] *= ar; Of[1][r] *= ar; Of[2][r] *= ar; Of[3][r] *= ar;
        }

        __syncthreads();   // P writes visible before re-read (belt & suspenders)

        // ---- PV: O[q][dh] += (Ph + Pl)[q][k] * V[k][dh] ----
        const bf16x8v pah = *(const bf16x8v*)&Psh[wq][l16][lg * 8];
        const bf16x8v pal = *(const bf16x8v*)&Psl[wq][l16][lg * 8];
        #pragma unroll
        for (int bb = 0; bb < 4; ++bb) {
            const bf16x8v bv = *(const bf16x8v*)&Vs[bb * 16 + l16][lg * 8];
            Of[bb] = __builtin_amdgcn_mfma_f32_16x16x32_bf16(pal, bv, Of[bb], 0, 0, 0);
            Of[bb] = __builtin_amdgcn_mfma_f32_16x16x32_bf16(pah, bv, Of[bb], 0, 0, 0);
        }
        __syncthreads();   // protect Ks/Vs before next-tile staging
    }

    // ---- epilogue: divide by row sums, store bf16 ----
    #pragma unroll
    for (int r = 0; r < 4; ++r) {
        const float inv = 1.0f / __shfl(lsum, lg * 4 + r);
        const int grow = b * Lq + qb * 64 + wq * 16 + lg * 4 + r;
        bf16* orow = O + (size_t)grow * DD + h * DHD;
        #pragma unroll
        for (int bb = 0; bb < 4; ++bb)
            orow[bb * 16 + l16] = __float2bfloat16(Of[bb][r] * inv);
    }
}

// ---------------- MoE router: fp32 LN recomputed in-kernel ----------
__global__ __launch_bounds__(64) void router_kernel(
    const float* __restrict__ X2,
    const float* __restrict__ g, const float* __restrict__ b,
    const float* __restrict__ rw, const float* __restrict__ rb,
    float* __restrict__ gates, int* __restrict__ ebuf, int* __restrict__ counts)
{
    int n = blockIdx.x;
    int lane = threadIdx.x;
    const float* xr = X2 + (size_t)n * DD;

    float v[16];
    #pragma unroll
    for (int i = 0; i < 16; ++i) v[i] = xr[lane + i * 64];

    float s = 0.f;
    #pragma unroll
    for (int i = 0; i < 16; ++i) s += v[i];
    #pragma unroll
    for (int off = 32; off > 0; off >>= 1) s += __shfl_xor(s, off);
    float mean = s * (1.0f / DD);

    float sq = 0.f;
    #pragma unroll
    for (int i = 0; i < 16; ++i) { float d = v[i] - mean; sq += d * d; }
    #pragma unroll
    for (int off = 32; off > 0; off >>= 1) sq += __shfl_xor(sq, off);
    float rstd = rsqrtf(sq * (1.0f / DD) + 1e-5f);

    float h[16];
    #pragma unroll
    for (int i = 0; i < 16; ++i) {
        int c = lane + i * 64;
        h[i] = (v[i] - mean) * rstd * g[c] + b[c];
    }

    float logit[EE];
    #pragma unroll
    for (int e = 0; e < EE; ++e) {
        const float* wr = rw + (size_t)e * DD;
        float p = 0.f;
        #pragma unroll
        for (int i = 0; i < 16; ++i) p += h[i] * wr[lane + i * 64];
        #pragma unroll
        for (int off = 32; off > 0; off >>= 1) p += __shfl_xor(p, off);
        logit[e] = p;
    }

    if (lane == 0) {
        #pragma unroll
        for (int e = 0; e < EE; ++e) logit[e] += rb[e];
        int i0 = 0;
        #pragma unroll
        for (int e = 1; e < EE; ++e) if (logit[e] > logit[i0]) i0 = e;
        int i1 = -1;
        #pragma unroll
        for (int e = 0; e < EE; ++e) {
            if (e == i0) continue;
            if (i1 < 0 || logit[e] > logit[i1]) i1 = e;
        }
        float ex = expf(logit[i1] - logit[i0]);
        float inv = 1.0f / (1.0f + ex);
        gates[2 * n + 0] = inv;
        gates[2 * n + 1] = ex * inv;
        ebuf[2 * n + 0] = i0;
        ebuf[2 * n + 1] = i1;
        atomicAdd(&counts[i0], 1);
        atomicAdd(&counts[i1], 1);
    }
}

__global__ void zero8_kernel(int* __restrict__ p) {
    if (threadIdx.x < EE) p[threadIdx.x] = 0;
}

__global__ void prefix_kernel(const int* __restrict__ counts,
                              int* __restrict__ seg_off, int* __restrict__ cursors) {
    if (threadIdx.x == 0) {
        int acc = 0;
        for (int e = 0; e < EE; ++e) { seg_off[e] = acc; cursors[e] = acc; acc += counts[e]; }
    }
}

__global__ __launch_bounds__(256) void scatter_kernel(
    const int* __restrict__ ebuf, int* __restrict__ cursors,
    int* __restrict__ tok_list, int* __restrict__ r_of)
{
    int n = blockIdx.x * 256 + threadIdx.x;
    if (n < NLAT) {
        for (int k = 0; k < 2; ++k) {
            int e = ebuf[2 * n + k];
            int r = atomicAdd(&cursors[e], 1);
            tok_list[r] = n;
            r_of[2 * n + k] = r;
        }
    }
}

__global__ __launch_bounds__(256) void mix_kernel(
    const float* __restrict__ X2, const bf16* __restrict__ EOUT,
    const float* __restrict__ gates, const int* __restrict__ r_of,
    float* __restrict__ out)
{
    int id = blockIdx.x * 256 + threadIdx.x;   // < NLAT*DD
    int n = id >> 10;
    int d = id & 1023;
    float v = X2[id]
            + gates[2 * n + 0] * toF(EOUT[(size_t)r_of[2 * n + 0] * DD + d])
            + gates[2 * n + 1] * toF(EOUT[(size_t)r_of[2 * n + 1] * DD + d]);
    out[id] = v;
}

// ---------------- Launcher ----------------
extern "C" void kernel_launch(void* const* d_in, const int* in_sizes, int n_in,
                              void* d_out, int out_size, void* d_ws, size_t ws_size,
                              hipStream_t stream)
{
    const float* latents  = (const float*)d_in[0];
    const float* tokens   = (const float*)d_in[1];
    const float* sa_ln_g  = (const float*)d_in[2];
    const float* sa_ln_b  = (const float*)d_in[3];
    const float* sa_in_w  = (const float*)d_in[4];
    const float* sa_in_b  = (const float*)d_in[5];
    const float* sa_out_w = (const float*)d_in[6];
    const float* sa_out_b = (const float*)d_in[7];
    const float* ca_q_ln_g  = (const float*)d_in[8];
    const float* ca_q_ln_b  = (const float*)d_in[9];
    const float* ca_kv_ln_g = (const float*)d_in[10];
    const float* ca_kv_ln_b = (const float*)d_in[11];
    const float* ca_in_w  = (const float*)d_in[12];
    const float* ca_in_b  = (const float*)d_in[13];
    const float* ca_out_w = (const float*)d_in[14];
    const float* ca_out_b = (const float*)d_in[15];
    const float* moe_ln_g = (const float*)d_in[16];
    const float* moe_ln_b = (const float*)d_in[17];
    const float* router_w = (const float*)d_in[18];
    const float* router_b = (const float*)d_in[19];
    const float* e_fc1_w  = (const float*)d_in[20];
    const float* e_fc1_b  = (const float*)d_in[21];
    const float* e_fc2_w  = (const float*)d_in[22];
    const float* e_fc2_b  = (const float*)d_in[23];

    // ---- workspace layout (liveness-based reuse; peak ~76 MB) ----
    char* base = (char*)d_ws;
    const size_t MB = (size_t)1 << 20;
    float* X1   = (float*)(base + 0 * MB);
    float* X2   = (float*)(base + 8 * MB);
    bf16*  H    = (bf16*) (base + 16 * MB);
    bf16*  AO   = (bf16*) (base + 20 * MB);
    bf16*  QCA  = (bf16*) (base + 24 * MB);
    bf16*  KVLN = (bf16*) (base + 28 * MB);
    bf16*  EOUT = (bf16*) (base + 28 * MB);
    bf16*  KVCA = (bf16*) (base + 44 * MB);
    bf16*  QKV  = (bf16*) (base + 44 * MB);
    bf16*  H1   = (bf16*) (base + 44 * MB);
    float* GATES = (float*)(base + 76 * MB);
    int* ebuf     = (int*)(base + 76 * MB + 16384);
    int* tok_list = ebuf + NASG;
    int* r_of     = tok_list + NASG;
    int* counts   = r_of + NASG;
    int* seg_off  = counts + EE;
    int* cursors  = seg_off + EE;

    // 1. SA LN
    ln_kernel<<<NLAT, 256, 0, stream>>>(latents, sa_ln_g, sa_ln_b, H);
    // 2. SA QKV projection (split weights: routing-sensitive path)
    {
        dim3 g(3072 / 128, NLAT / 128, 1);
        mfma_gemm_kernel<<<g, 256, 0, stream>>>(H, sa_in_w, sa_in_b, QKV, nullptr,
                                                NLAT, 3072, DD,
                                                nullptr, 0, 1, nullptr, nullptr, nullptr);
    }
    // 3. SA attention (MFMA flash)
    attn_mfma_kernel<<<BB * HH * (LL / 64), 256, 0, stream>>>(
        QKV, 3072, 0, QKV, 3072, 1024, 2048, AO, LL, LL);
    // 4. X1 = latents + AO @ sa_out_w^T + b
    {
        dim3 g(DD / 128, NLAT / 128, 1);
        mfma_gemm_kernel<<<g, 256, 0, stream>>>(AO, sa_out_w, sa_out_b, nullptr, X1,
                                                NLAT, DD, DD,
                                                latents, 0, 1, nullptr, nullptr, nullptr);
    }
    // 5. CA q-LN
    ln_kernel<<<NLAT, 256, 0, stream>>>(X1, ca_q_ln_g, ca_q_ln_b, H);
    // 6. CA kv-LN of tokens
    ln_kernel<<<NTOK, 256, 0, stream>>>(tokens, ca_kv_ln_g, ca_kv_ln_b, KVLN);
    // 7. CA Q projection
    {
        dim3 g(DD / 128, NLAT / 128, 1);
        mfma_gemm_kernel<<<g, 256, 0, stream>>>(H, ca_in_w, ca_in_b, QCA, nullptr,
                                                NLAT, DD, DD,
                                                nullptr, 0, 1, nullptr, nullptr, nullptr);
    }
    // 8. CA K,V projection
    {
        dim3 g(2048 / 128, NTOK / 128, 1);
        mfma_gemm_kernel<<<g, 256, 0, stream>>>(KVLN, ca_in_w + (size_t)1024 * DD, ca_in_b + 1024,
                                                KVCA, nullptr, NTOK, 2048, DD,
                                                nullptr, 0, 1, nullptr, nullptr, nullptr);
    }
    // 9. CA attention (MFMA flash)
    attn_mfma_kernel<<<BB * HH * (LL / 64), 256, 0, stream>>>(
        QCA, 1024, 0, KVCA, 2048, 0, 1024, AO, LL, TT);
    // 10. X2 = X1 + AO @ ca_out_w^T + b
    {
        dim3 g(DD / 128, NLAT / 128, 1);
        mfma_gemm_kernel<<<g, 256, 0, stream>>>(AO, ca_out_w, ca_out_b, nullptr, X2,
                                                NLAT, DD, DD,
                                                X1, 0, 1, nullptr, nullptr, nullptr);
    }
    // 11. MoE LN
    ln_kernel<<<NLAT, 256, 0, stream>>>(X2, moe_ln_g, moe_ln_b, H);
    // 12-15. Routing
    zero8_kernel<<<1, 64, 0, stream>>>(counts);
    router_kernel<<<NLAT, 64, 0, stream>>>(X2, moe_ln_g, moe_ln_b, router_w, router_b,
                                           GATES, ebuf, counts);
    prefix_kernel<<<1, 64, 0, stream>>>(counts, seg_off, cursors);
    scatter_kernel<<<NLAT / 256, 256, 0, stream>>>(ebuf, cursors, tok_list, r_of);
    // 16. fc1 grouped (gelu); plain bf16 weights (post-routing path)
    {
        dim3 g(DFFD / 128, NLAT / 128, EE);
        mfma_gemm_kernel<<<g, 256, 0, stream>>>(H, e_fc1_w, e_fc1_b, H1, nullptr,
                                                0, DFFD, DD,
                                                nullptr, 1, 0, tok_list, seg_off, counts);
    }
    // 17. fc2 grouped
    {
        dim3 g(DD / 128, NLAT / 128, EE);
        mfma_gemm_kernel<<<g, 256, 0, stream>>>(H1, e_fc2_w, e_fc2_b, EOUT, nullptr,
                                                0, DD, DFFD,
                                                nullptr, 0, 0, nullptr, seg_off, counts);
    }
    // 18. Mix + residual
    mix_kernel<<<(NLAT * DD) / 256, 256, 0, stream>>>(X2, EOUT, GATES, r_of, (float*)d_out);
}

// Round 4
// 1175.361 us; speedup vs baseline: 4.1253x; 1.0310x over previous
//
#include <hip/hip_runtime.h>
#include <hip/hip_bf16.h>
#include <math.h>

typedef __hip_bfloat16 bf16;
typedef __bf16 bf16x8v __attribute__((ext_vector_type(8)));
typedef float f32x4 __attribute__((ext_vector_type(4)));
typedef unsigned short us8v __attribute__((ext_vector_type(8)));

// Problem dims
#define DD   1024
#define HH   16
#define DHD  64
#define EE   8
#define BB   4
#define LL   512
#define TT   2048
#define DFFD 4096
#define NLAT 2048   // B*L
#define NTOK 8192   // B*T
#define NASG 4096   // 2 * NLAT

__device__ __forceinline__ float toF(float x) { return x; }
__device__ __forceinline__ float toF(bf16 x) { return __bfloat162float(x); }
__device__ __forceinline__ float us2f(unsigned short u) {
    union { unsigned int i; float f; } v; v.i = ((unsigned int)u) << 16; return v.f;
}
__device__ __forceinline__ unsigned short f2us(float f) {
    bf16 t = __float2bfloat16(f);
    return *(unsigned short*)&t;
}

// ---------------- LayerNorm: one block (256 thr) per row, D=1024 --------------
__device__ __forceinline__ float block_sum256(float val, float* red) {
    #pragma unroll
    for (int off = 32; off > 0; off >>= 1) val += __shfl_down(val, off);
    if ((threadIdx.x & 63) == 0) red[threadIdx.x >> 6] = val;
    __syncthreads();
    if (threadIdx.x == 0) red[4] = red[0] + red[1] + red[2] + red[3];
    __syncthreads();
    float r = red[4];
    __syncthreads();
    return r;
}

__global__ __launch_bounds__(256) void ln_kernel(
    const float* __restrict__ x, const float* __restrict__ g, const float* __restrict__ b,
    bf16* __restrict__ out)
{
    __shared__ float red[5];
    int row = blockIdx.x;
    int tid = threadIdx.x;
    const float* xr = x + (size_t)row * DD;
    float v[4];
    #pragma unroll
    for (int i = 0; i < 4; ++i) v[i] = xr[tid + i * 256];
    float s = v[0] + v[1] + v[2] + v[3];
    float mean = block_sum256(s, red) * (1.0f / DD);
    float sq = 0.f;
    #pragma unroll
    for (int i = 0; i < 4; ++i) { float d = v[i] - mean; sq += d * d; }
    float var = block_sum256(sq, red) * (1.0f / DD);
    float rstd = rsqrtf(var + 1e-5f);
    bf16* orow = out + (size_t)row * DD;
    #pragma unroll
    for (int i = 0; i < 4; ++i) {
        int c = tid + i * 256;
        orow[c] = __float2bfloat16((v[i] - mean) * rstd * g[c] + b[c]);
    }
}

// ---------------- MFMA GEMM: C[M,N] = A[M,K](bf16) * W[N,K](f32->bf16)^T ------
// 128x128 tile, BK=32, 256 threads / 4 waves (each wave = 64x64 out).
// 2-phase register-prefetch pipeline: next tile's global loads are issued right
// after the staging barrier, so they fly during ds_read+MFMA of the current
// tile (R3 counters showed the serialized version latency-bound: MfmaUtil 7.6%,
// VALUBusy 4.5%, occupancy 11%).
// SPLIT=1: stages Wh=bf16(W) AND Wl=bf16(W-Wh), 2 MFMAs (18-bit weights,
// routing-safe, pre-router path). SPLIT=0: Wh only (post-routing experts),
// and the Wl LDS array is compiled out (16KB vs 24KB -> more blocks/CU).
// MFMA order per acc element identical to R3 (Wl then Wh) -> bit-identical.
// Requires K % 64 == 0 (holds: K = 1024 or 4096).
template<int SPLIT>
__global__ __launch_bounds__(256) void mfma_gemm_t(
    const bf16* __restrict__ A, const float* __restrict__ W,
    const float* __restrict__ bias,
    bf16* __restrict__ Cb, float* __restrict__ Cf,
    int M, int N, int K,
    const float* __restrict__ res, int act,
    const int* __restrict__ gather,
    const int* __restrict__ seg_off, const int* __restrict__ seg_cnt)
{
    int m_base = 0, mrows = M;
    if (seg_off) {
        int e = blockIdx.z;
        m_base = seg_off[e];
        mrows  = seg_cnt[e];
        W    += (size_t)e * N * K;
        bias += (size_t)e * N;
    }
    const int m0 = blockIdx.y * 128;
    if (m0 >= mrows) return;
    const int n0 = blockIdx.x * 128;

    constexpr int HALF = 4 * 128 * 8;                 // one [kg][row][8] plane
    __shared__ bf16 smem[(SPLIT ? 3 : 2) * HALF];
    bf16* AsB = smem;                                  // A plane
    bf16* WhB = smem + HALF;                           // W-high plane
    bf16* WlB = smem + 2 * HALF;                       // W-low plane (SPLIT only)

    const int tid  = threadIdx.x;
    const int wid  = tid >> 6;
    const int lane = tid & 63;
    const int lg   = lane >> 4;
    const int l16  = lane & 15;
    const int mb   = (wid >> 1) * 64;   // wave row base in tile
    const int nb   = (wid & 1) * 64;    // wave col base in tile

    const int srow  = tid >> 1;         // 0..127 staging row
    const int shalf = tid & 1;          // which 16-k half
    const int kg0   = shalf * 2;

    const bool a_ok = (m0 + srow) < mrows;
    const unsigned short* aptr = nullptr;
    if (a_ok) {
        int grow = m_base + m0 + srow;
        int asrc = gather ? gather[grow] : grow;
        aptr = (const unsigned short*)(A + (size_t)asrc * K + shalf * 16);
    }
    const float* wptr = W + (size_t)(n0 + srow) * K + shalf * 16;

    f32x4 acc[4][4] = {};

    auto load_tile = [&](us8v (&ar)[2], float4 (&wr)[4], int kk) {
        if (a_ok) {
            ar[0] = *(const us8v*)(aptr + kk);
            ar[1] = *(const us8v*)(aptr + kk + 8);
        }
        wr[0] = *(const float4*)(wptr + kk);
        wr[1] = *(const float4*)(wptr + kk + 4);
        wr[2] = *(const float4*)(wptr + kk + 8);
        wr[3] = *(const float4*)(wptr + kk + 12);
    };

    auto store_tile = [&](const us8v (&ar)[2], const float4 (&wr)[4]) {
        *(us8v*)(AsB + ((size_t)kg0 * 128 + srow) * 8)       = ar[0];
        *(us8v*)(AsB + ((size_t)(kg0 + 1) * 128 + srow) * 8) = ar[1];
        const float fw[16] = {wr[0].x, wr[0].y, wr[0].z, wr[0].w,
                              wr[1].x, wr[1].y, wr[1].z, wr[1].w,
                              wr[2].x, wr[2].y, wr[2].z, wr[2].w,
                              wr[3].x, wr[3].y, wr[3].z, wr[3].w};
        us8v hi0, hi1;
        if constexpr (SPLIT) {
            us8v lo0, lo1;
            #pragma unroll
            for (int j = 0; j < 8; ++j) {
                unsigned short h0 = f2us(fw[j]);
                unsigned short h1 = f2us(fw[j + 8]);
                hi0[j] = h0; hi1[j] = h1;
                lo0[j] = f2us(fw[j] - us2f(h0));
                lo1[j] = f2us(fw[j + 8] - us2f(h1));
            }
            *(us8v*)(WlB + ((size_t)kg0 * 128 + srow) * 8)       = lo0;
            *(us8v*)(WlB + ((size_t)(kg0 + 1) * 128 + srow) * 8) = lo1;
        } else {
            #pragma unroll
            for (int j = 0; j < 8; ++j) {
                hi0[j] = f2us(fw[j]);
                hi1[j] = f2us(fw[j + 8]);
            }
        }
        *(us8v*)(WhB + ((size_t)kg0 * 128 + srow) * 8)       = hi0;
        *(us8v*)(WhB + ((size_t)(kg0 + 1) * 128 + srow) * 8) = hi1;
    };

    auto compute = [&]() {
        bf16x8v af[4];
        #pragma unroll
        for (int i = 0; i < 4; ++i)
            af[i] = *(const bf16x8v*)(AsB + ((size_t)lg * 128 + mb + i * 16 + l16) * 8);
        if constexpr (SPLIT) {
            #pragma unroll
            for (int j = 0; j < 4; ++j) {
                bf16x8v wlf = *(const bf16x8v*)(WlB + ((size_t)lg * 128 + nb + j * 16 + l16) * 8);
                #pragma unroll
                for (int i = 0; i < 4; ++i)
                    acc[i][j] = __builtin_amdgcn_mfma_f32_16x16x32_bf16(af[i], wlf, acc[i][j], 0, 0, 0);
            }
        }
        #pragma unroll
        for (int j = 0; j < 4; ++j) {
            bf16x8v wf = *(const bf16x8v*)(WhB + ((size_t)lg * 128 + nb + j * 16 + l16) * 8);
            #pragma unroll
            for (int i = 0; i < 4; ++i)
                acc[i][j] = __builtin_amdgcn_mfma_f32_16x16x32_bf16(af[i], wf, acc[i][j], 0, 0, 0);
        }
    };

    us8v a0[2] = {}, a1[2] = {};
    float4 w0r[4], w1r[4];
    load_tile(a0, w0r, 0);

    for (int k0 = 0; k0 < K; k0 += 64) {
        store_tile(a0, w0r);
        __syncthreads();
        load_tile(a1, w1r, k0 + 32);        // in flight during compute
        compute();
        __syncthreads();

        store_tile(a1, w1r);
        __syncthreads();
        const int kn = k0 + 64;
        if (kn < K) load_tile(a0, w0r, kn); // in flight during compute
        compute();
        __syncthreads();
    }

    // ---- epilogue: D layout col=l16 (n), row = lg*4 + reg (m within 16) ----
    #pragma unroll
    for (int i = 0; i < 4; ++i) {
        #pragma unroll
        for (int r = 0; r < 4; ++r) {
            int mm = m0 + mb + i * 16 + lg * 4 + r;
            if (mm >= mrows) continue;
            size_t crow = (size_t)(m_base + mm);
            #pragma unroll
            for (int j = 0; j < 4; ++j) {
                int nn = n0 + nb + j * 16 + l16;
                float v = acc[i][j][r] + bias[nn];
                if (act == 1) v = 0.5f * v * (1.0f + erff(v * 0.70710678118654752f));
                if (res) v += res[crow * (size_t)N + nn];
                if (Cb) Cb[crow * (size_t)N + nn] = __float2bfloat16(v);
                else    Cf[crow * (size_t)N + nn] = v;
            }
        }
    }
}

// ---------------- Attention (MFMA flash): 4 waves/block, 64 q rows/block ------
// Swapped QK^T: S^T = mfma(A=K, B=Q); D layout col=lane&15 (=q), row=4*lg+reg
// (=key). Softmax per q-row is in-register + shfl_xor(16/32). P is carried in
// SPLIT bf16 (high + low residual) so P*V is effectively f32-accurate.
__global__ __launch_bounds__(256) void attn_mfma_kernel(
    const bf16* __restrict__ Q, int ldq, int qoff,
    const bf16* __restrict__ KV, int ldk, int koff, int voff,
    bf16* __restrict__ O, int Lq, int Tk)
{
    __shared__ bf16 Qs[64][72];
    __shared__ bf16 Ks[32][72];
    __shared__ bf16 Vs[64][40];        // transposed V: [dh][k]
    __shared__ bf16 Psh[4][16][40];    // per-wave P tile [q][k], bf16 high
    __shared__ bf16 Psl[4][16][40];    // bf16 low residual (p - bf16(p))

    const int nqb = Lq >> 6;
    const int qb  = blockIdx.x % nqb;
    const int h   = (blockIdx.x / nqb) % HH;
    const int b   = blockIdx.x / (nqb * HH);

    const int tid  = threadIdx.x;
    const int wq   = tid >> 6;
    const int lane = tid & 63;
    const int lg   = lane >> 4;
    const int l16  = lane & 15;

    // ---- stage Q tile (pre-scaled by 1/sqrt(64)=0.125 — exact in bf16) ----
    {
        const int row = tid >> 2;
        const int c0  = (tid & 3) * 16;
        const unsigned short* src = (const unsigned short*)
            (Q + (size_t)(b * Lq + qb * 64 + row) * ldq + qoff + h * DHD + c0);
        #pragma unroll
        for (int hf = 0; hf < 2; ++hf) {
            us8v v = *(const us8v*)(src + hf * 8);
            us8v o;
            #pragma unroll
            for (int j = 0; j < 8; ++j) o[j] = f2us(us2f(v[j]) * 0.125f);
            *(us8v*)&Qs[row][c0 + hf * 8] = o;
        }
    }
    __syncthreads();

    const int qrow = wq * 16 + l16;
    const bf16x8v fQ0 = *(const bf16x8v*)&Qs[qrow][lg * 8];
    const bf16x8v fQ1 = *(const bf16x8v*)&Qs[qrow][32 + lg * 8];

    float m = -1e30f, lsum = 0.f;
    f32x4 Of[4] = {};

    const size_t kvbase = (size_t)b * Tk * ldk;
    const int kst_k = tid >> 3;          // 0..31
    const int kst_c = (tid & 7) * 8;     // dh chunk
    const int vst_k = (tid & 15) * 2;    // key pair
    const int vst_d = (tid >> 4) * 4;    // dh base

    for (int t0 = 0; t0 < Tk; t0 += 32) {
        // stage K tile [32][64]
        {
            const bf16* ks = KV + kvbase + (size_t)(t0 + kst_k) * ldk + koff + h * DHD + kst_c;
            *(float4*)&Ks[kst_k][kst_c] = *(const float4*)ks;
        }
        // stage V tile transposed -> Vs[dh][k]
        {
            const bf16* vsrc = KV + kvbase + (size_t)(t0 + vst_k) * ldk + voff + h * DHD + vst_d;
            ushort4 a = *(const ushort4*)vsrc;
            ushort4 c = *(const ushort4*)(vsrc + ldk);
            unsigned int w;
            w = (unsigned)a.x | ((unsigned)c.x << 16); *(unsigned*)&Vs[vst_d + 0][vst_k] = w;
            w = (unsigned)a.y | ((unsigned)c.y << 16); *(unsigned*)&Vs[vst_d + 1][vst_k] = w;
            w = (unsigned)a.z | ((unsigned)c.z << 16); *(unsigned*)&Vs[vst_d + 2][vst_k] = w;
            w = (unsigned)a.w | ((unsigned)c.w << 16); *(unsigned*)&Vs[vst_d + 3][vst_k] = w;
        }
        __syncthreads();

        // ---- QK^T: S^T[k][q], keys 0..15 in st0, 16..31 in st1 ----
        f32x4 st0 = {}, st1 = {};
        {
            const bf16x8v k00 = *(const bf16x8v*)&Ks[l16][lg * 8];
            const bf16x8v k10 = *(const bf16x8v*)&Ks[16 + l16][lg * 8];
            const bf16x8v k01 = *(const bf16x8v*)&Ks[l16][32 + lg * 8];
            const bf16x8v k11 = *(const bf16x8v*)&Ks[16 + l16][32 + lg * 8];
            st0 = __builtin_amdgcn_mfma_f32_16x16x32_bf16(k00, fQ0, st0, 0, 0, 0);
            st1 = __builtin_amdgcn_mfma_f32_16x16x32_bf16(k10, fQ0, st1, 0, 0, 0);
            st0 = __builtin_amdgcn_mfma_f32_16x16x32_bf16(k01, fQ1, st0, 0, 0, 0);
            st1 = __builtin_amdgcn_mfma_f32_16x16x32_bf16(k11, fQ1, st1, 0, 0, 0);
        }

        // ---- online softmax for row q = l16 (f32, expf: matches reference) ----
        float cm = fmaxf(fmaxf(fmaxf(st0[0], st0[1]), fmaxf(st0[2], st0[3])),
                         fmaxf(fmaxf(st1[0], st1[1]), fmaxf(st1[2], st1[3])));
        cm = fmaxf(cm, __shfl_xor(cm, 16));
        cm = fmaxf(cm, __shfl_xor(cm, 32));
        const float nm = fmaxf(m, cm);
        float p0[4], p1[4];
        float ps = 0.f;
        #pragma unroll
        for (int r = 0; r < 4; ++r) { p0[r] = expf(st0[r] - nm); ps += p0[r]; }
        #pragma unroll
        for (int r = 0; r < 4; ++r) { p1[r] = expf(st1[r] - nm); ps += p1[r]; }
        ps += __shfl_xor(ps, 16);
        ps += __shfl_xor(ps, 32);
        const float alpha = expf(m - nm);
        lsum = lsum * alpha + ps;
        m = nm;

        // ---- write split-P tile: Psh = bf16(p), Psl = bf16(p - Psh) ----
        ushort4 h0, h1, lo0, lo1;
        #pragma unroll
        for (int r = 0; r < 4; ++r) {
            unsigned short hh = f2us(p0[r]);
            ((unsigned short*)&h0)[r]  = hh;
            ((unsigned short*)&lo0)[r] = f2us(p0[r] - us2f(hh));
        }
        #pragma unroll
        for (int r = 0; r < 4; ++r) {
            unsigned short hh = f2us(p1[r]);
            ((unsigned short*)&h1)[r]  = hh;
            ((unsigned short*)&lo1)[r] = f2us(p1[r] - us2f(hh));
        }
        *(ushort4*)&Psh[wq][l16][lg * 4]      = h0;
        *(ushort4*)&Psh[wq][l16][16 + lg * 4] = h1;
        *(ushort4*)&Psl[wq][l16][lg * 4]      = lo0;
        *(ushort4*)&Psl[wq][l16][16 + lg * 4] = lo1;

        // ---- rescale O accumulators (row q' = 4*lg + r) ----
        #pragma unroll
        for (int r = 0; r < 4; ++r) {
            const float ar = __shfl(alpha, lg * 4 + r);
            Of[0][r] *= ar; Of[1][r] *= ar; Of[2][r] *= ar; Of[3][r] *= ar;
        }

        __syncthreads();   // P writes visible before re-read

        // ---- PV: O[q][dh] += (Ph + Pl)[q][k] * V[k][dh] ----
        const bf16x8v pah = *(const bf16x8v*)&Psh[wq][l16][lg * 8];
        const bf16x8v pal = *(const bf16x8v*)&Psl[wq][l16][lg * 8];
        #pragma unroll
        for (int bb = 0; bb < 4; ++bb) {
            const bf16x8v bv = *(const bf16x8v*)&Vs[bb * 16 + l16][lg * 8];
            Of[bb] = __builtin_amdgcn_mfma_f32_16x16x32_bf16(pal, bv, Of[bb], 0, 0, 0);
            Of[bb] = __builtin_amdgcn_mfma_f32_16x16x32_bf16(pah, bv, Of[bb], 0, 0, 0);
        }
        __syncthreads();   // protect Ks/Vs before next-tile staging
    }

    // ---- epilogue: divide by row sums, store bf16 ----
    #pragma unroll
    for (int r = 0; r < 4; ++r) {
        const float inv = 1.0f / __shfl(lsum, lg * 4 + r);
        const int grow = b * Lq + qb * 64 + wq * 16 + lg * 4 + r;
        bf16* orow = O + (size_t)grow * DD + h * DHD;
        #pragma unroll
        for (int bb = 0; bb < 4; ++bb)
            orow[bb * 16 + l16] = __float2bfloat16(Of[bb][r] * inv);
    }
}

// ---------------- MoE router: fp32 LN recomputed in-kernel ----------
__global__ __launch_bounds__(64) void router_kernel(
    const float* __restrict__ X2,
    const float* __restrict__ g, const float* __restrict__ b,
    const float* __restrict__ rw, const float* __restrict__ rb,
    float* __restrict__ gates, int* __restrict__ ebuf, int* __restrict__ counts)
{
    int n = blockIdx.x;
    int lane = threadIdx.x;
    const float* xr = X2 + (size_t)n * DD;

    float v[16];
    #pragma unroll
    for (int i = 0; i < 16; ++i) v[i] = xr[lane + i * 64];

    float s = 0.f;
    #pragma unroll
    for (int i = 0; i < 16; ++i) s += v[i];
    #pragma unroll
    for (int off = 32; off > 0; off >>= 1) s += __shfl_xor(s, off);
    float mean = s * (1.0f / DD);

    float sq = 0.f;
    #pragma unroll
    for (int i = 0; i < 16; ++i) { float d = v[i] - mean; sq += d * d; }
    #pragma unroll
    for (int off = 32; off > 0; off >>= 1) sq += __shfl_xor(sq, off);
    float rstd = rsqrtf(sq * (1.0f / DD) + 1e-5f);

    float h[16];
    #pragma unroll
    for (int i = 0; i < 16; ++i) {
        int c = lane + i * 64;
        h[i] = (v[i] - mean) * rstd * g[c] + b[c];
    }

    float logit[EE];
    #pragma unroll
    for (int e = 0; e < EE; ++e) {
        const float* wr = rw + (size_t)e * DD;
        float p = 0.f;
        #pragma unroll
        for (int i = 0; i < 16; ++i) p += h[i] * wr[lane + i * 64];
        #pragma unroll
        for (int off = 32; off > 0; off >>= 1) p += __shfl_xor(p, off);
        logit[e] = p;
    }

    if (lane == 0) {
        #pragma unroll
        for (int e = 0; e < EE; ++e) logit[e] += rb[e];
        int i0 = 0;
        #pragma unroll
        for (int e = 1; e < EE; ++e) if (logit[e] > logit[i0]) i0 = e;
        int i1 = -1;
        #pragma unroll
        for (int e = 0; e < EE; ++e) {
            if (e == i0) continue;
            if (i1 < 0 || logit[e] > logit[i1]) i1 = e;
        }
        float ex = expf(logit[i1] - logit[i0]);
        float inv = 1.0f / (1.0f + ex);
        gates[2 * n + 0] = inv;
        gates[2 * n + 1] = ex * inv;
        ebuf[2 * n + 0] = i0;
        ebuf[2 * n + 1] = i1;
        atomicAdd(&counts[i0], 1);
        atomicAdd(&counts[i1], 1);
    }
}

__global__ void zero8_kernel(int* __restrict__ p) {
    if (threadIdx.x < EE) p[threadIdx.x] = 0;
}

__global__ void prefix_kernel(const int* __restrict__ counts,
                              int* __restrict__ seg_off, int* __restrict__ cursors) {
    if (threadIdx.x == 0) {
        int acc = 0;
        for (int e = 0; e < EE; ++e) { seg_off[e] = acc; cursors[e] = acc; acc += counts[e]; }
    }
}

__global__ __launch_bounds__(256) void scatter_kernel(
    const int* __restrict__ ebuf, int* __restrict__ cursors,
    int* __restrict__ tok_list, int* __restrict__ r_of)
{
    int n = blockIdx.x * 256 + threadIdx.x;
    if (n < NLAT) {
        for (int k = 0; k < 2; ++k) {
            int e = ebuf[2 * n + k];
            int r = atomicAdd(&cursors[e], 1);
            tok_list[r] = n;
            r_of[2 * n + k] = r;
        }
    }
}

__global__ __launch_bounds__(256) void mix_kernel(
    const float* __restrict__ X2, const bf16* __restrict__ EOUT,
    const float* __restrict__ gates, const int* __restrict__ r_of,
    float* __restrict__ out)
{
    int id = blockIdx.x * 256 + threadIdx.x;   // < NLAT*DD
    int n = id >> 10;
    int d = id & 1023;
    float v = X2[id]
            + gates[2 * n + 0] * toF(EOUT[(size_t)r_of[2 * n + 0] * DD + d])
            + gates[2 * n + 1] * toF(EOUT[(size_t)r_of[2 * n + 1] * DD + d]);
    out[id] = v;
}

// ---------------- Launcher ----------------
extern "C" void kernel_launch(void* const* d_in, const int* in_sizes, int n_in,
                              void* d_out, int out_size, void* d_ws, size_t ws_size,
                              hipStream_t stream)
{
    const float* latents  = (const float*)d_in[0];
    const float* tokens   = (const float*)d_in[1];
    const float* sa_ln_g  = (const float*)d_in[2];
    const float* sa_ln_b  = (const float*)d_in[3];
    const float* sa_in_w  = (const float*)d_in[4];
    const float* sa_in_b  = (const float*)d_in[5];
    const float* sa_out_w = (const float*)d_in[6];
    const float* sa_out_b = (const float*)d_in[7];
    const float* ca_q_ln_g  = (const float*)d_in[8];
    const float* ca_q_ln_b  = (const float*)d_in[9];
    const float* ca_kv_ln_g = (const float*)d_in[10];
    const float* ca_kv_ln_b = (const float*)d_in[11];
    const float* ca_in_w  = (const float*)d_in[12];
    const float* ca_in_b  = (const float*)d_in[13];
    const float* ca_out_w = (const float*)d_in[14];
    const float* ca_out_b = (const float*)d_in[15];
    const float* moe_ln_g = (const float*)d_in[16];
    const float* moe_ln_b = (const float*)d_in[17];
    const float* router_w = (const float*)d_in[18];
    const float* router_b = (const float*)d_in[19];
    const float* e_fc1_w  = (const float*)d_in[20];
    const float* e_fc1_b  = (const float*)d_in[21];
    const float* e_fc2_w  = (const float*)d_in[22];
    const float* e_fc2_b  = (const float*)d_in[23];

    // ---- workspace layout (liveness-based reuse; peak ~76 MB) ----
    char* base = (char*)d_ws;
    const size_t MB = (size_t)1 << 20;
    float* X1   = (float*)(base + 0 * MB);
    float* X2   = (float*)(base + 8 * MB);
    bf16*  H    = (bf16*) (base + 16 * MB);
    bf16*  AO   = (bf16*) (base + 20 * MB);
    bf16*  QCA  = (bf16*) (base + 24 * MB);
    bf16*  KVLN = (bf16*) (base + 28 * MB);
    bf16*  EOUT = (bf16*) (base + 28 * MB);
    bf16*  KVCA = (bf16*) (base + 44 * MB);
    bf16*  QKV  = (bf16*) (base + 44 * MB);
    bf16*  H1   = (bf16*) (base + 44 * MB);
    float* GATES = (float*)(base + 76 * MB);
    int* ebuf     = (int*)(base + 76 * MB + 16384);
    int* tok_list = ebuf + NASG;
    int* r_of     = tok_list + NASG;
    int* counts   = r_of + NASG;
    int* seg_off  = counts + EE;
    int* cursors  = seg_off + EE;

    // 1. SA LN
    ln_kernel<<<NLAT, 256, 0, stream>>>(latents, sa_ln_g, sa_ln_b, H);
    // 2. SA QKV projection (split weights: routing-sensitive path)
    {
        dim3 g(3072 / 128, NLAT / 128, 1);
        mfma_gemm_t<1><<<g, 256, 0, stream>>>(H, sa_in_w, sa_in_b, QKV, nullptr,
                                              NLAT, 3072, DD,
                                              nullptr, 0, nullptr, nullptr, nullptr);
    }
    // 3. SA attention (MFMA flash)
    attn_mfma_kernel<<<BB * HH * (LL / 64), 256, 0, stream>>>(
        QKV, 3072, 0, QKV, 3072, 1024, 2048, AO, LL, LL);
    // 4. X1 = latents + AO @ sa_out_w^T + b
    {
        dim3 g(DD / 128, NLAT / 128, 1);
        mfma_gemm_t<1><<<g, 256, 0, stream>>>(AO, sa_out_w, sa_out_b, nullptr, X1,
                                              NLAT, DD, DD,
                                              latents, 0, nullptr, nullptr, nullptr);
    }
    // 5. CA q-LN
    ln_kernel<<<NLAT, 256, 0, stream>>>(X1, ca_q_ln_g, ca_q_ln_b, H);
    // 6. CA kv-LN of tokens
    ln_kernel<<<NTOK, 256, 0, stream>>>(tokens, ca_kv_ln_g, ca_kv_ln_b, KVLN);
    // 7. CA Q projection
    {
        dim3 g(DD / 128, NLAT / 128, 1);
        mfma_gemm_t<1><<<g, 256, 0, stream>>>(H, ca_in_w, ca_in_b, QCA, nullptr,
                                              NLAT, DD, DD,
                                              nullptr, 0, nullptr, nullptr, nullptr);
    }
    // 8. CA K,V projection
    {
        dim3 g(2048 / 128, NTOK / 128, 1);
        mfma_gemm_t<1><<<g, 256, 0, stream>>>(KVLN, ca_in_w + (size_t)1024 * DD, ca_in_b + 1024,
                                              KVCA, nullptr, NTOK, 2048, DD,
                                              nullptr, 0, nullptr, nullptr, nullptr);
    }
    // 9. CA attention (MFMA flash)
    attn_mfma_kernel<<<BB * HH * (LL / 64), 256, 0, stream>>>(
        QCA, 1024, 0, KVCA, 2048, 0, 1024, AO, LL, TT);
    // 10. X2 = X1 + AO @ ca_out_w^T + b
    {
        dim3 g(DD / 128, NLAT / 128, 1);
        mfma_gemm_t<1><<<g, 256, 0, stream>>>(AO, ca_out_w, ca_out_b, nullptr, X2,
                                              NLAT, DD, DD,
                                              X1, 0, nullptr, nullptr, nullptr);
    }
    // 11. MoE LN
    ln_kernel<<<NLAT, 256, 0, stream>>>(X2, moe_ln_g, moe_ln_b, H);
    // 12-15. Routing
    zero8_kernel<<<1, 64, 0, stream>>>(counts);
    router_kernel<<<NLAT, 64, 0, stream>>>(X2, moe_ln_g, moe_ln_b, router_w, router_b,
                                           GATES, ebuf, counts);
    prefix_kernel<<<1, 64, 0, stream>>>(counts, seg_off, cursors);
    scatter_kernel<<<NLAT / 256, 256, 0, stream>>>(ebuf, cursors, tok_list, r_of);
    // 16. fc1 grouped (gelu); plain bf16 weights (post-routing path)
    {
        dim3 g(DFFD / 128, NLAT / 128, EE);
        mfma_gemm_t<0><<<g, 256, 0, stream>>>(H, e_fc1_w, e_fc1_b, H1, nullptr,
                                              0, DFFD, DD,
                                              nullptr, 1, tok_list, seg_off, counts);
    }
    // 17. fc2 grouped
    {
        dim3 g(DD / 128, NLAT / 128, EE);
        mfma_gemm_t<0><<<g, 256, 0, stream>>>(H1, e_fc2_w, e_fc2_b, EOUT, nullptr,
                                              0, DD, DFFD,
                                              nullptr, 0, nullptr, seg_off, counts);
    }
    // 18. Mix + residual
    mix_kernel<<<(NLAT * DD) / 256, 256, 0, stream>>>(X2, EOUT, GATES, r_of, (float*)d_out);
}